// Round 18
// baseline (178.868 us; speedup 1.0000x reference)
//
#include <hip/hip_runtime.h>
#include <hip/hip_bf16.h>
#include <math.h>

#define NNODES 100000
#define NNBRS  16
#define NBLK   ((NNODES + 127) / 128)   // k_projx grid = 782
#define KRA    ((NBLK + 7) / 8)         // kredA grid = 98

typedef short  s16x8 __attribute__((ext_vector_type(8)));
typedef ushort u16x8 __attribute__((ext_vector_type(8)));
typedef float  f32x4 __attribute__((ext_vector_type(4)));

__device__ __forceinline__ float nonneg_(float w) { return w > 0.f ? w + 1.f : __expf(w); }
__device__ __forceinline__ float sigmoid_(float w) { return 1.f / (1.f + __expf(-w)); }
__device__ __forceinline__ ushort f2b(float f) {
    unsigned u = __builtin_bit_cast(unsigned, f);
    return (ushort)((u + 0x7FFFu + ((u >> 16) & 1u)) >> 16);
}
__device__ __forceinline__ float b2f(ushort h) {
    return __builtin_bit_cast(float, (unsigned)h << 16);
}
__device__ __forceinline__ short fbh(float f) {
    __hip_bfloat16 h = __float2bfloat16(f);
    return __builtin_bit_cast(short, h);
}
__device__ __forceinline__ s16x8 cvt8(float4 lo, float4 hi) {
    s16x8 r;
    r[0] = fbh(lo.x); r[1] = fbh(lo.y); r[2] = fbh(lo.z); r[3] = fbh(lo.w);
    r[4] = fbh(hi.x); r[5] = fbh(hi.y); r[6] = fbh(hi.z); r[7] = fbh(hi.w);
    return r;
}

// lgkm-only barrier: keeps global loads in flight across it
#define BAR() do {                                             \
    __builtin_amdgcn_sched_barrier(0);                         \
    asm volatile("s_waitcnt lgkmcnt(0)" ::: "memory");         \
    __builtin_amdgcn_sched_barrier(0);                         \
    __builtin_amdgcn_s_barrier();                              \
    __builtin_amdgcn_sched_barrier(0);                         \
} while (0)

// ---------------- sums of sigmoid (parallel, atomic) ------------------------
__global__ __launch_bounds__(256) void k_sumsig(const float* __restrict__ qlw,
                                                const float* __restrict__ qgw,
                                                float* __restrict__ sums) {
    __shared__ float rr[8];
    const int tid = threadIdx.x, lane = tid & 63, wv = tid >> 6;
    const int base = blockIdx.x * 512;
    float s0 = sigmoid_(qlw[base + tid]) + sigmoid_(qlw[base + 256 + tid]);
    float s1 = sigmoid_(qgw[base + tid]) + sigmoid_(qgw[base + 256 + tid]);
#pragma unroll
    for (int o = 32; o > 0; o >>= 1) {
        s0 += __shfl_down(s0, o);
        s1 += __shfl_down(s1, o);
    }
    if (lane == 0) { rr[wv] = s0; rr[4 + wv] = s1; }
    __syncthreads();
    if (tid == 0) atomicAdd(&sums[0], rr[0] + rr[1] + rr[2] + rr[3]);
    if (tid == 1) atomicAdd(&sums[1], rr[4] + rr[5] + rr[6] + rr[7]);
}

// ---------------- build transformed bf16 weight tables ----------------------
__global__ __launch_bounds__(256) void k_prep(const float* __restrict__ qk_ego,
                                              const float* __restrict__ qlw,
                                              const float* __restrict__ klw,
                                              const float* __restrict__ qgw,
                                              const float* __restrict__ ve,
                                              const float* __restrict__ vl,
                                              const float* __restrict__ vg,
                                              const float* __restrict__ bias_b,
                                              ushort* __restrict__ B1t,
                                              ushort* __restrict__ Vt,
                                              float* __restrict__ biasvec) {
    int idx = blockIdx.x * 256 + threadIdx.x;
    if (idx < 128 * 512) {
        int o = idx >> 9, k = idx & 511;
        float v;
        if (o < 32)       v = qk_ego[o * 512 + k];
        else if (o < 64)  v = sigmoid_(qlw[(o - 32) * 512 + k]);
        else if (o < 96)  v = nonneg_(klw[(o - 64) * 512 + k]);
        else              v = sigmoid_(qgw[(o - 96) * 512 + k]);
        B1t[idx] = f2b(v);
    } else if (idx < 128 * 512 + 512 * 96) {
        int j = idx - 128 * 512;
        int d = j / 96, e = j % 96;
        const float* src = (e < 32) ? ve : (e < 64 ? vl : vg);
        Vt[j] = f2b(nonneg_(src[d * 32 + (e & 31)]));
    } else if (idx < 128 * 512 + 512 * 96 + 512) {
        int d = idx - 128 * 512 - 512 * 96;
        float b = bias_b[d];
        biasvec[d] = (b > 0.f ? b + 1.f : __expf(b));
    }
}

// ---------------- k_projx v3: 64-col segments, 48KB LDS, 3 blocks/CU --------
// r17 counters: MfmaUtil 4%, VALUBusy 7%, BW 1.07TB/s, Occupancy 19% ->
// latency-bound with all pipes idle. Fix per roofline table: SMALLER LDS
// tiles. Segments halve to 64 cols (8 segs x 2 MFMA-steps); As/Bs 16KB each
// in one Sh[2] block (epilogue restage still has 32KB); cs 16KB; total 48KB
// -> 3 blocks/CU = 6 waves/SIMD (+50% latency hiding). launch_bounds(512,6)
// pins VGPR<=85 (staging regs halved vs r15; r16's spill mode avoided).
__global__ __launch_bounds__(512, 6) void k_projx(const float* __restrict__ x,
                                                  const ushort* __restrict__ B1t,
                                                  ushort* __restrict__ ego_a,
                                                  ushort* __restrict__ qloc_a,
                                                  ushort* __restrict__ kloc_a,
                                                  ushort* __restrict__ qglob_a,
                                                  float* __restrict__ xcs) {
    __shared__ ushort Sh[2][128 * 64];  // 32 KB: [0]=A seg tile, [1]=B seg tile
    __shared__ float  cs[8][512];       // 16 KB: per-wave colsum partials
    ushort* As = Sh[0];
    ushort* Bs = Sh[1];
    const int t = threadIdx.x, lane = t & 63, w = t >> 6;   // 8 waves
    const int lr = lane & 15, g = lane >> 4;
    const int row0 = blockIdx.x * 128;
    const int arow_ = t >> 3;          // 0..63 (A-stage row within p-group)
    const int acol_ = (t & 7) * 8;     // 0..56 (A-stage col in floats, fixed)
    const char* B1tc = (const char*)B1t;

    uint4 bst[2];
#define BLOAD(seg) { _Pragma("unroll")                                        \
    for (int c = 0; c < 2; c++) {                                             \
        int l = c * 512 + t; int r = l >> 3; int sl = l & 7;                  \
        bst[c] = *(const uint4*)(B1tc + r * 1024 + (seg) * 128 + sl * 16);    \
    } }
#define BWRITE() { _Pragma("unroll")                                          \
    for (int c = 0; c < 2; c++) {                                             \
        int l = c * 512 + t; int r = l >> 3; int sl = l & 7;                  \
        *(uint4*)((char*)Bs + r * 128 + ((sl * 16) ^ ((r & 7) << 4))) =       \
            bst[c];                                                           \
    } }

    float4 al0[2], al1[2];
#define ALOAD(seg) { _Pragma("unroll")                                        \
    for (int p = 0; p < 2; p++) {                                             \
        int rr = p * 64 + arow_;                                              \
        int grow = row0 + rr; if (grow > NNODES - 1) grow = NNODES - 1;       \
        const float* sp = x + (size_t)grow * 512 + (seg) * 64 + acol_;        \
        al0[p] = *(const float4*)(sp);                                        \
        al1[p] = *(const float4*)(sp + 4);                                    \
    } }
// AWRITE: cvt+LDS write + colsum accumulate + 8-lane-group reduce into cs.
#define AWRITE(seg) {                                                         \
    float a8[8] = {0.f,0.f,0.f,0.f,0.f,0.f,0.f,0.f};                          \
    _Pragma("unroll")                                                         \
    for (int p = 0; p < 2; p++) {                                             \
        int rr = p * 64 + arow_;                                              \
        if (row0 + rr < NNODES) {                                             \
            a8[0]+=al0[p].x; a8[1]+=al0[p].y; a8[2]+=al0[p].z; a8[3]+=al0[p].w;\
            a8[4]+=al1[p].x; a8[5]+=al1[p].y; a8[6]+=al1[p].z; a8[7]+=al1[p].w;\
        }                                                                     \
        *(s16x8*)((char*)As + rr * 128 + ((acol_ * 2) ^ ((rr & 7) << 4))) =   \
            cvt8(al0[p], al1[p]);                                             \
    }                                                                         \
    _Pragma("unroll")                                                         \
    for (int j = 0; j < 8; j++) {                                             \
        a8[j] += __shfl_xor(a8[j], 8);                                        \
        a8[j] += __shfl_xor(a8[j], 16);                                       \
        a8[j] += __shfl_xor(a8[j], 32);                                       \
    }                                                                         \
    if ((lane >> 3) == 0) { _Pragma("unroll")                                 \
        for (int j = 0; j < 8; j++)                                           \
            cs[w][(seg) * 64 + lane * 8 + j] = a8[j];                         \
    } }

    f32x4 acc[8];
#pragma unroll
    for (int n = 0; n < 8; n++) acc[n] = (f32x4){0.f, 0.f, 0.f, 0.f};

    ALOAD(0)
    BLOAD(0)
    AWRITE(0)
    BWRITE()
    BAR();

#pragma unroll
    for (int seg = 0; seg < 8; seg++) {
        if (seg < 7) { ALOAD(seg + 1) BLOAD(seg + 1) }   // in flight over MFMA
#pragma unroll
        for (int st = 0; st < 2; st++) {
            const int ar = w * 16 + lr;
            s16x8 af = *(const s16x8*)((const char*)As + ar * 128 +
                                       ((st * 64 + g * 16) ^ ((ar & 7) << 4)));
#pragma unroll
            for (int n = 0; n < 8; n++) {
                s16x8 bf = *(const s16x8*)((const char*)Bs + (n * 16 + lr) * 128 +
                                           ((st * 64 + g * 16) ^ ((lr & 7) << 4)));
                acc[n] = __builtin_amdgcn_mfma_f32_16x16x32_bf16(af, bf, acc[n], 0, 0, 0);
            }
        }
        if (seg < 7) {
            BAR();       // all reads of this segment done
            AWRITE(seg + 1)
            BWRITE()
            BAR();       // writes visible
        }
    }
#undef ALOAD
#undef AWRITE
#undef BLOAD
#undef BWRITE

    // ---- epilogue: restage frags in Sh (32KB), wide stores; xcs from cs ----
    __syncthreads();                 // all As/Bs reads + cs writes done
    if (t < 512) {
        float s = cs[0][t] + cs[1][t] + cs[2][t] + cs[3][t]
                + cs[4][t] + cs[5][t] + cs[6][t] + cs[7][t];
        xcs[(size_t)blockIdx.x * 512 + t] = s;
    }
    char* regn = (char*)Sh + w * 4096;        // per-wave 16 rows x 256 B
#pragma unroll
    for (int n = 0; n < 8; n++) {
        const int col = (n >> 1) * 32 + (n & 1) * 16 + lr;
#pragma unroll
        for (int i = 0; i < 4; i++) {
            int row = g * 4 + i;
            *(ushort*)(regn + row * 256 + ((col * 2) ^ ((row & 7) << 4))) =
                f2b(acc[n][i]);
        }
    }
    {
        const int rr = lane & 15, a2 = lane >> 4;
        uint4 v0 = *(const uint4*)(regn + rr * 256 + (( 0 + a2 * 64) ^ ((rr & 7) << 4)));
        uint4 v1 = *(const uint4*)(regn + rr * 256 + ((16 + a2 * 64) ^ ((rr & 7) << 4)));
        uint4 v2 = *(const uint4*)(regn + rr * 256 + ((32 + a2 * 64) ^ ((rr & 7) << 4)));
        uint4 v3 = *(const uint4*)(regn + rr * 256 + ((48 + a2 * 64) ^ ((rr & 7) << 4)));
        int grow = row0 + w * 16 + rr;
        if (grow < NNODES) {
            ushort* ap = (a2 == 0) ? ego_a : (a2 == 1) ? qloc_a
                        : (a2 == 2) ? kloc_a : qglob_a;
            uint4* dp = (uint4*)(ap + (size_t)grow * 32);
            dp[0] = v0; dp[1] = v1; dp[2] = v2; dp[3] = v3;
        }
    }
}

// ---------------- kredA: 98 blocks sum 8 xcs rows each -> csum2 -------------
__global__ __launch_bounds__(256) void k_kredA(const float* __restrict__ xcs,
                                               float* __restrict__ csum2) {
    const int t = threadIdx.x, b = blockIdx.x;
    float s1 = 0.f, s2 = 0.f;
#pragma unroll
    for (int r = 0; r < 8; r++) {
        int row = b * 8 + r;
        if (row < NBLK) {
            s1 += xcs[(size_t)row * 512 + t];
            s2 += xcs[(size_t)row * 512 + 256 + t];
        }
    }
    csum2[(size_t)b * 512 + t] = s1;
    csum2[(size_t)b * 512 + 256 + t] = s2;
}

// ---------------- kredB: final colsum + kacc = cs . nonneg(kgw)^T -----------
__global__ __launch_bounds__(256) void k_kredB(const float* __restrict__ csum2,
                                               const float* __restrict__ kgw,
                                               float* __restrict__ kacc) {
    __shared__ float cs[512];
    const int t = threadIdx.x;
    float s0 = 0.f, s1 = 0.f;
    for (int b = 0; b < KRA; b++) {
        s0 += csum2[(size_t)b * 512 + t];
        s1 += csum2[(size_t)b * 512 + 256 + t];
    }
    cs[t] = s0; cs[256 + t] = s1;
    __syncthreads();
    const int e = t >> 3, j = t & 7;         // 8 threads per output e
    float p = 0.f;
    for (int d = j * 64; d < j * 64 + 64; d++)
        p += cs[d] * nonneg_(kgw[e * 512 + d]);
    p += __shfl_xor(p, 1);
    p += __shfl_xor(p, 2);
    p += __shfl_xor(p, 4);
    if (j == 0) kacc[e] = p;
}

// ---------------- fused v5 (r10/r14): chunked LDS stage + NT writeback ------
__global__ __launch_bounds__(256, 4) void k_fused(const ushort* __restrict__ ego_a,
                                                  const ushort* __restrict__ qloc_a,
                                                  const ushort* __restrict__ kloc_a,
                                                  const ushort* __restrict__ qglob_a,
                                                  const int* __restrict__ src,
                                                  const float* __restrict__ kacc,
                                                  const float* __restrict__ sums,
                                                  const ushort* __restrict__ Vt,
                                                  const float* __restrict__ biasvec,
                                                  float* __restrict__ out) {
    __shared__ float4 stg4[2048];            // 32 KB: 64 rows x 512 B
    char* stg = (char*)stg4;
    const int t = threadIdx.x, lane = t & 63, w = t >> 6;
    const int lr = lane & 15, g = lane >> 4;
    const int node = blockIdx.x * 64 + w * 16 + lr;
    const int nc = node < NNODES ? node : NNODES - 1;

    const float inv = 1.f / 512.f;
    const float inv2 = inv * inv;
    const float scl = inv2 / sums[0];
    const float scg = inv2 / sums[1] * (1.f / (float)NNODES);
    float kg[8];
    {
        float4 kg0 = *(const float4*)(kacc + g * 8);
        float4 kg1 = *(const float4*)(kacc + g * 8 + 4);
        kg[0]=kg0.x; kg[1]=kg0.y; kg[2]=kg0.z; kg[3]=kg0.w;
        kg[4]=kg1.x; kg[5]=kg1.y; kg[6]=kg1.z; kg[7]=kg1.w;
    }

    // ---- scores for this wave's 16 nodes ----
    s16x8 p0, p1, p2;
    {
        u16x8 e8 = *(const u16x8*)(ego_a   + (size_t)nc * 32 + g * 8);
        u16x8 q8 = *(const u16x8*)(qloc_a  + (size_t)nc * 32 + g * 8);
        u16x8 g8 = *(const u16x8*)(qglob_a + (size_t)nc * 32 + g * 8);
        int4 si0 = *(const int4*)(src + (size_t)nc * 16);
        int4 si1 = *(const int4*)(src + (size_t)nc * 16 + 4);
        int4 si2 = *(const int4*)(src + (size_t)nc * 16 + 8);
        int4 si3 = *(const int4*)(src + (size_t)nc * 16 + 12);
        float ks[8] = {0.f,0.f,0.f,0.f,0.f,0.f,0.f,0.f};
#define GAT(sn) {                                                             \
        u16x8 kv = *(const u16x8*)(kloc_a + (size_t)(sn) * 32 + g * 8);       \
        _Pragma("unroll")                                                     \
        for (int j = 0; j < 8; j++) ks[j] += b2f(kv[j]);                      \
    }
        GAT(si0.x) GAT(si0.y) GAT(si0.z) GAT(si0.w)
        GAT(si1.x) GAT(si1.y) GAT(si1.z) GAT(si1.w)
        GAT(si2.x) GAT(si2.y) GAT(si2.z) GAT(si2.w)
        GAT(si3.x) GAT(si3.y) GAT(si3.z) GAT(si3.w)
#undef GAT
        float se[8], sl[8], sg[8];
        float tt = 0.f;
#pragma unroll
        for (int j = 0; j < 8; j++) {
            float e = b2f(e8[j]) * inv;
            se[j] = e * e;
            sl[j] = b2f(q8[j]) * ks[j] * scl;
            sg[j] = b2f(g8[j]) * kg[j] * scg;
            tt += se[j] + sl[j] + sg[j];
        }
        tt += __shfl_xor(tt, 16);
        tt += __shfl_xor(tt, 32);
        float is = 1.f / (0.001f + tt);
#pragma unroll
        for (int j = 0; j < 8; j++) {
            p0[j] = (short)f2b(se[j] * is);
            p1[j] = (short)f2b(sl[j] * is);
            p2[j] = (short)f2b(sg[j] * is);
        }
    }

    // ---- 4 groups of 8 oc-tiles: MFMA -> 32KB LDS -> 4KB NT streaming stores
    const int srow = w * 16 + lr;
    const int sxor = (srow & 7) << 4;
#pragma unroll
    for (int gi = 0; gi < 4; gi++) {
        if (gi) __syncthreads();             // prev writeback reads done
#pragma unroll
        for (int m2 = 0; m2 < 8; m2++) {
            const int m = gi * 8 + m2;
            const ushort* vp = Vt + (size_t)(m * 16 + lr) * 96 + g * 8;
            s16x8 a0 = *(const s16x8*)(vp);
            s16x8 a1 = *(const s16x8*)(vp + 32);
            s16x8 a2 = *(const s16x8*)(vp + 64);
            f32x4 dA = (f32x4){0.f,0.f,0.f,0.f};
            dA = __builtin_amdgcn_mfma_f32_16x16x32_bf16(a0, p0, dA, 0, 0, 0);
            dA = __builtin_amdgcn_mfma_f32_16x16x32_bf16(a1, p1, dA, 0, 0, 0);
            dA = __builtin_amdgcn_mfma_f32_16x16x32_bf16(a2, p2, dA, 0, 0, 0);
            float4 bb = *(const float4*)(biasvec + m * 16 + g * 4);
            float4 o4 = {dA[0]+bb.x, dA[1]+bb.y, dA[2]+bb.z, dA[3]+bb.w};
            *(float4*)(stg + srow * 512 + ((m2 * 64 + g * 16) ^ sxor)) = o4;
        }
        __syncthreads();
        // writeback: 8 iters x 4KB contiguous (2 rows x 512B per wave-instr)
#pragma unroll
        for (int k = 0; k < 8; k++) {
            const int lin = k * 1024 + t * 4;    // float idx in 64x128 tile
            const int row = lin >> 7, inrow = lin & 127;
            f32x4 v = *(const f32x4*)(stg + row * 512 +
                                      ((inrow * 4) ^ ((row & 7) << 4)));
            const int gnode = blockIdx.x * 64 + row;
            if (gnode < NNODES)
                __builtin_nontemporal_store(
                    v, (f32x4*)(out + (size_t)gnode * 512 + gi * 128 + inrow));
        }
    }
}

extern "C" void kernel_launch(void* const* d_in, const int* in_sizes, int n_in,
                              void* d_out, int out_size, void* d_ws, size_t ws_size,
                              hipStream_t stream) {
    (void)in_sizes; (void)n_in; (void)out_size; (void)ws_size;
    const int*   adj    = (const int*)d_in[0];    // row0 = src
    const float* x      = (const float*)d_in[1];
    const float* qk_ego = (const float*)d_in[2];
    const float* v_ego  = (const float*)d_in[3];
    const float* qlw    = (const float*)d_in[4];
    const float* klw    = (const float*)d_in[5];
    const float* vl     = (const float*)d_in[6];
    const float* qgw    = (const float*)d_in[7];
    const float* kgw    = (const float*)d_in[8];
    const float* vg     = (const float*)d_in[9];
    const float* bias_b = (const float*)d_in[10];
    float* out = (float*)d_out;
    float* ws  = (float*)d_ws;

    // ws layout (float offsets)
    float*  kacc    = ws;                          // 32
    float*  sums    = ws + 32;                     // 2
    float*  biasvec = ws + 64;                     // 512
    ushort* B1t     = (ushort*)(ws + 1024);        // 128*512 bf16 -> 32768 fl
    ushort* Vt      = (ushort*)(ws + 33792);       // 512*96 bf16  -> 24576 fl
    ushort* ego_a   = (ushort*)(ws + 65536);                // N*32 bf16
    ushort* qloc_a  = (ushort*)(ws + 65536 + 1600000);      // N*32 bf16
    ushort* kloc_a  = (ushort*)(ws + 65536 + 3200000);      // N*32 bf16
    ushort* qglob_a = (ushort*)(ws + 65536 + 4800000);      // N*32 bf16
    float*  xcs     = ws + 6465536;                         // NBLK*512 fp32
    float*  csum2   = ws + 6465536 + 400384;                // KRA*512 fp32

    (void)hipMemsetAsync(sums, 0, 2 * sizeof(float), stream);
    k_sumsig<<<32, 256, 0, stream>>>(qlw, qgw, sums);
    {
        int total = 128 * 512 + 512 * 96 + 512;
        k_prep<<<(total + 255) / 256, 256, 0, stream>>>(qk_ego, qlw, klw, qgw,
                                                        v_ego, vl, vg, bias_b,
                                                        B1t, Vt, biasvec);
    }
    k_projx<<<NBLK, 512, 0, stream>>>(x, B1t, ego_a, qloc_a, kloc_a, qglob_a, xcs);
    k_kredA<<<KRA, 256, 0, stream>>>(xcs, csum2);
    k_kredB<<<1, 256, 0, stream>>>(csum2, kgw, kacc);
    k_fused<<<(NNODES + 63) / 64, 256, 0, stream>>>(ego_a, qloc_a, kloc_a, qglob_a,
                                                    adj, kacc, sums, Vt, biasvec, out);
}

// Round 19
// 155.181 us; speedup vs baseline: 1.1526x; 1.1526x over previous
//
#include <hip/hip_runtime.h>
#include <hip/hip_bf16.h>
#include <math.h>

#define NNODES 100000
#define NNBRS  16
#define NBLK   ((NNODES + 127) / 128)   // k_projx grid = 782
#define KRA    ((NBLK + 7) / 8)         // kredA grid = 98

typedef short  s16x8 __attribute__((ext_vector_type(8)));
typedef ushort u16x8 __attribute__((ext_vector_type(8)));
typedef float  f32x4 __attribute__((ext_vector_type(4)));

__device__ __forceinline__ float nonneg_(float w) { return w > 0.f ? w + 1.f : __expf(w); }
__device__ __forceinline__ float sigmoid_(float w) { return 1.f / (1.f + __expf(-w)); }
__device__ __forceinline__ ushort f2b(float f) {
    unsigned u = __builtin_bit_cast(unsigned, f);
    return (ushort)((u + 0x7FFFu + ((u >> 16) & 1u)) >> 16);
}
__device__ __forceinline__ float b2f(ushort h) {
    return __builtin_bit_cast(float, (unsigned)h << 16);
}
__device__ __forceinline__ short fbh(float f) {
    __hip_bfloat16 h = __float2bfloat16(f);
    return __builtin_bit_cast(short, h);
}
__device__ __forceinline__ s16x8 cvt8(float4 lo, float4 hi) {
    s16x8 r;
    r[0] = fbh(lo.x); r[1] = fbh(lo.y); r[2] = fbh(lo.z); r[3] = fbh(lo.w);
    r[4] = fbh(hi.x); r[5] = fbh(hi.y); r[6] = fbh(hi.z); r[7] = fbh(hi.w);
    return r;
}

// lgkm-only barrier: keeps global loads in flight across it
#define BAR() do {                                             \
    __builtin_amdgcn_sched_barrier(0);                         \
    asm volatile("s_waitcnt lgkmcnt(0)" ::: "memory");         \
    __builtin_amdgcn_sched_barrier(0);                         \
    __builtin_amdgcn_s_barrier();                              \
    __builtin_amdgcn_sched_barrier(0);                         \
} while (0)

// ---------------- sums of sigmoid (parallel, atomic) ------------------------
__global__ __launch_bounds__(256) void k_sumsig(const float* __restrict__ qlw,
                                                const float* __restrict__ qgw,
                                                float* __restrict__ sums) {
    __shared__ float rr[8];
    const int tid = threadIdx.x, lane = tid & 63, wv = tid >> 6;
    const int base = blockIdx.x * 512;
    float s0 = sigmoid_(qlw[base + tid]) + sigmoid_(qlw[base + 256 + tid]);
    float s1 = sigmoid_(qgw[base + tid]) + sigmoid_(qgw[base + 256 + tid]);
#pragma unroll
    for (int o = 32; o > 0; o >>= 1) {
        s0 += __shfl_down(s0, o);
        s1 += __shfl_down(s1, o);
    }
    if (lane == 0) { rr[wv] = s0; rr[4 + wv] = s1; }
    __syncthreads();
    if (tid == 0) atomicAdd(&sums[0], rr[0] + rr[1] + rr[2] + rr[3]);
    if (tid == 1) atomicAdd(&sums[1], rr[4] + rr[5] + rr[6] + rr[7]);
}

// ---------------- build transformed bf16 weight tables ----------------------
__global__ __launch_bounds__(256) void k_prep(const float* __restrict__ qk_ego,
                                              const float* __restrict__ qlw,
                                              const float* __restrict__ klw,
                                              const float* __restrict__ qgw,
                                              const float* __restrict__ ve,
                                              const float* __restrict__ vl,
                                              const float* __restrict__ vg,
                                              const float* __restrict__ bias_b,
                                              ushort* __restrict__ B1t,
                                              ushort* __restrict__ Vt,
                                              float* __restrict__ biasvec) {
    int idx = blockIdx.x * 256 + threadIdx.x;
    if (idx < 128 * 512) {
        int o = idx >> 9, k = idx & 511;
        float v;
        if (o < 32)       v = qk_ego[o * 512 + k];
        else if (o < 64)  v = sigmoid_(qlw[(o - 32) * 512 + k]);
        else if (o < 96)  v = nonneg_(klw[(o - 64) * 512 + k]);
        else              v = sigmoid_(qgw[(o - 96) * 512 + k]);
        B1t[idx] = f2b(v);
    } else if (idx < 128 * 512 + 512 * 96) {
        int j = idx - 128 * 512;
        int d = j / 96, e = j % 96;
        const float* src = (e < 32) ? ve : (e < 64 ? vl : vg);
        Vt[j] = f2b(nonneg_(src[d * 32 + (e & 31)]));
    } else if (idx < 128 * 512 + 512 * 96 + 512) {
        int d = idx - 128 * 512 - 512 * 96;
        float b = bias_b[d];
        biasvec[d] = (b > 0.f ? b + 1.f : __expf(b));
    }
}

// ---------------- k_projx v3b: 64-col segments, 48KB LDS, VGPR cap 128 ------
// r18's (512,6) bound forced VGPR=40 with acc spilled to scratch (FETCH
// +33MB, WRITE +36MB) -- occupancy rose 19->51% but spill traffic ate it.
// v3b: identical structure, launch_bounds(512,4) (VGPR<=128). Natural demand
// ~75-90 VGPR -> no spill, HW still fits 6 waves/SIMD (512-reg pool / ~85),
// LDS 48KB -> 3 blocks/CU.
__global__ __launch_bounds__(512, 4) void k_projx(const float* __restrict__ x,
                                                  const ushort* __restrict__ B1t,
                                                  ushort* __restrict__ ego_a,
                                                  ushort* __restrict__ qloc_a,
                                                  ushort* __restrict__ kloc_a,
                                                  ushort* __restrict__ qglob_a,
                                                  float* __restrict__ xcs) {
    __shared__ ushort Sh[2][128 * 64];  // 32 KB: [0]=A seg tile, [1]=B seg tile
    __shared__ float  cs[8][512];       // 16 KB: per-wave colsum partials
    ushort* As = Sh[0];
    ushort* Bs = Sh[1];
    const int t = threadIdx.x, lane = t & 63, w = t >> 6;   // 8 waves
    const int lr = lane & 15, g = lane >> 4;
    const int row0 = blockIdx.x * 128;
    const int arow_ = t >> 3;          // 0..63 (A-stage row within p-group)
    const int acol_ = (t & 7) * 8;     // 0..56 (A-stage col in floats, fixed)
    const char* B1tc = (const char*)B1t;

    uint4 bst[2];
#define BLOAD(seg) { _Pragma("unroll")                                        \
    for (int c = 0; c < 2; c++) {                                             \
        int l = c * 512 + t; int r = l >> 3; int sl = l & 7;                  \
        bst[c] = *(const uint4*)(B1tc + r * 1024 + (seg) * 128 + sl * 16);    \
    } }
#define BWRITE() { _Pragma("unroll")                                          \
    for (int c = 0; c < 2; c++) {                                             \
        int l = c * 512 + t; int r = l >> 3; int sl = l & 7;                  \
        *(uint4*)((char*)Bs + r * 128 + ((sl * 16) ^ ((r & 7) << 4))) =       \
            bst[c];                                                           \
    } }

    float4 al0[2], al1[2];
#define ALOAD(seg) { _Pragma("unroll")                                        \
    for (int p = 0; p < 2; p++) {                                             \
        int rr = p * 64 + arow_;                                              \
        int grow = row0 + rr; if (grow > NNODES - 1) grow = NNODES - 1;       \
        const float* sp = x + (size_t)grow * 512 + (seg) * 64 + acol_;        \
        al0[p] = *(const float4*)(sp);                                        \
        al1[p] = *(const float4*)(sp + 4);                                    \
    } }
// AWRITE: cvt+LDS write + colsum accumulate + 8-lane-group reduce into cs.
#define AWRITE(seg) {                                                         \
    float a8[8] = {0.f,0.f,0.f,0.f,0.f,0.f,0.f,0.f};                          \
    _Pragma("unroll")                                                         \
    for (int p = 0; p < 2; p++) {                                             \
        int rr = p * 64 + arow_;                                              \
        if (row0 + rr < NNODES) {                                             \
            a8[0]+=al0[p].x; a8[1]+=al0[p].y; a8[2]+=al0[p].z; a8[3]+=al0[p].w;\
            a8[4]+=al1[p].x; a8[5]+=al1[p].y; a8[6]+=al1[p].z; a8[7]+=al1[p].w;\
        }                                                                     \
        *(s16x8*)((char*)As + rr * 128 + ((acol_ * 2) ^ ((rr & 7) << 4))) =   \
            cvt8(al0[p], al1[p]);                                             \
    }                                                                         \
    _Pragma("unroll")                                                         \
    for (int j = 0; j < 8; j++) {                                             \
        a8[j] += __shfl_xor(a8[j], 8);                                        \
        a8[j] += __shfl_xor(a8[j], 16);                                       \
        a8[j] += __shfl_xor(a8[j], 32);                                       \
    }                                                                         \
    if ((lane >> 3) == 0) { _Pragma("unroll")                                 \
        for (int j = 0; j < 8; j++)                                           \
            cs[w][(seg) * 64 + lane * 8 + j] = a8[j];                         \
    } }

    f32x4 acc[8];
#pragma unroll
    for (int n = 0; n < 8; n++) acc[n] = (f32x4){0.f, 0.f, 0.f, 0.f};

    ALOAD(0)
    BLOAD(0)
    AWRITE(0)
    BWRITE()
    BAR();

#pragma unroll
    for (int seg = 0; seg < 8; seg++) {
        if (seg < 7) { ALOAD(seg + 1) BLOAD(seg + 1) }   // in flight over MFMA
#pragma unroll
        for (int st = 0; st < 2; st++) {
            const int ar = w * 16 + lr;
            s16x8 af = *(const s16x8*)((const char*)As + ar * 128 +
                                       ((st * 64 + g * 16) ^ ((ar & 7) << 4)));
#pragma unroll
            for (int n = 0; n < 8; n++) {
                s16x8 bf = *(const s16x8*)((const char*)Bs + (n * 16 + lr) * 128 +
                                           ((st * 64 + g * 16) ^ ((lr & 7) << 4)));
                acc[n] = __builtin_amdgcn_mfma_f32_16x16x32_bf16(af, bf, acc[n], 0, 0, 0);
            }
        }
        if (seg < 7) {
            BAR();       // all reads of this segment done
            AWRITE(seg + 1)
            BWRITE()
            BAR();       // writes visible
        }
    }
#undef ALOAD
#undef AWRITE
#undef BLOAD
#undef BWRITE

    // ---- epilogue: restage frags in Sh (32KB), wide stores; xcs from cs ----
    __syncthreads();                 // all As/Bs reads + cs writes done
    if (t < 512) {
        float s = cs[0][t] + cs[1][t] + cs[2][t] + cs[3][t]
                + cs[4][t] + cs[5][t] + cs[6][t] + cs[7][t];
        xcs[(size_t)blockIdx.x * 512 + t] = s;
    }
    char* regn = (char*)Sh + w * 4096;        // per-wave 16 rows x 256 B
#pragma unroll
    for (int n = 0; n < 8; n++) {
        const int col = (n >> 1) * 32 + (n & 1) * 16 + lr;
#pragma unroll
        for (int i = 0; i < 4; i++) {
            int row = g * 4 + i;
            *(ushort*)(regn + row * 256 + ((col * 2) ^ ((row & 7) << 4))) =
                f2b(acc[n][i]);
        }
    }
    {
        const int rr = lane & 15, a2 = lane >> 4;
        uint4 v0 = *(const uint4*)(regn + rr * 256 + (( 0 + a2 * 64) ^ ((rr & 7) << 4)));
        uint4 v1 = *(const uint4*)(regn + rr * 256 + ((16 + a2 * 64) ^ ((rr & 7) << 4)));
        uint4 v2 = *(const uint4*)(regn + rr * 256 + ((32 + a2 * 64) ^ ((rr & 7) << 4)));
        uint4 v3 = *(const uint4*)(regn + rr * 256 + ((48 + a2 * 64) ^ ((rr & 7) << 4)));
        int grow = row0 + w * 16 + rr;
        if (grow < NNODES) {
            ushort* ap = (a2 == 0) ? ego_a : (a2 == 1) ? qloc_a
                        : (a2 == 2) ? kloc_a : qglob_a;
            uint4* dp = (uint4*)(ap + (size_t)grow * 32);
            dp[0] = v0; dp[1] = v1; dp[2] = v2; dp[3] = v3;
        }
    }
}

// ---------------- kredA: 98 blocks sum 8 xcs rows each -> csum2 -------------
__global__ __launch_bounds__(256) void k_kredA(const float* __restrict__ xcs,
                                               float* __restrict__ csum2) {
    const int t = threadIdx.x, b = blockIdx.x;
    float s1 = 0.f, s2 = 0.f;
#pragma unroll
    for (int r = 0; r < 8; r++) {
        int row = b * 8 + r;
        if (row < NBLK) {
            s1 += xcs[(size_t)row * 512 + t];
            s2 += xcs[(size_t)row * 512 + 256 + t];
        }
    }
    csum2[(size_t)b * 512 + t] = s1;
    csum2[(size_t)b * 512 + 256 + t] = s2;
}

// ---------------- kredB: final colsum + kacc = cs . nonneg(kgw)^T -----------
__global__ __launch_bounds__(256) void k_kredB(const float* __restrict__ csum2,
                                               const float* __restrict__ kgw,
                                               float* __restrict__ kacc) {
    __shared__ float cs[512];
    const int t = threadIdx.x;
    float s0 = 0.f, s1 = 0.f;
    for (int b = 0; b < KRA; b++) {
        s0 += csum2[(size_t)b * 512 + t];
        s1 += csum2[(size_t)b * 512 + 256 + t];
    }
    cs[t] = s0; cs[256 + t] = s1;
    __syncthreads();
    const int e = t >> 3, j = t & 7;         // 8 threads per output e
    float p = 0.f;
    for (int d = j * 64; d < j * 64 + 64; d++)
        p += cs[d] * nonneg_(kgw[e * 512 + d]);
    p += __shfl_xor(p, 1);
    p += __shfl_xor(p, 2);
    p += __shfl_xor(p, 4);
    if (j == 0) kacc[e] = p;
}

// ---------------- fused v5 (r10/r14): chunked LDS stage + NT writeback ------
__global__ __launch_bounds__(256, 4) void k_fused(const ushort* __restrict__ ego_a,
                                                  const ushort* __restrict__ qloc_a,
                                                  const ushort* __restrict__ kloc_a,
                                                  const ushort* __restrict__ qglob_a,
                                                  const int* __restrict__ src,
                                                  const float* __restrict__ kacc,
                                                  const float* __restrict__ sums,
                                                  const ushort* __restrict__ Vt,
                                                  const float* __restrict__ biasvec,
                                                  float* __restrict__ out) {
    __shared__ float4 stg4[2048];            // 32 KB: 64 rows x 512 B
    char* stg = (char*)stg4;
    const int t = threadIdx.x, lane = t & 63, w = t >> 6;
    const int lr = lane & 15, g = lane >> 4;
    const int node = blockIdx.x * 64 + w * 16 + lr;
    const int nc = node < NNODES ? node : NNODES - 1;

    const float inv = 1.f / 512.f;
    const float inv2 = inv * inv;
    const float scl = inv2 / sums[0];
    const float scg = inv2 / sums[1] * (1.f / (float)NNODES);
    float kg[8];
    {
        float4 kg0 = *(const float4*)(kacc + g * 8);
        float4 kg1 = *(const float4*)(kacc + g * 8 + 4);
        kg[0]=kg0.x; kg[1]=kg0.y; kg[2]=kg0.z; kg[3]=kg0.w;
        kg[4]=kg1.x; kg[5]=kg1.y; kg[6]=kg1.z; kg[7]=kg1.w;
    }

    // ---- scores for this wave's 16 nodes ----
    s16x8 p0, p1, p2;
    {
        u16x8 e8 = *(const u16x8*)(ego_a   + (size_t)nc * 32 + g * 8);
        u16x8 q8 = *(const u16x8*)(qloc_a  + (size_t)nc * 32 + g * 8);
        u16x8 g8 = *(const u16x8*)(qglob_a + (size_t)nc * 32 + g * 8);
        int4 si0 = *(const int4*)(src + (size_t)nc * 16);
        int4 si1 = *(const int4*)(src + (size_t)nc * 16 + 4);
        int4 si2 = *(const int4*)(src + (size_t)nc * 16 + 8);
        int4 si3 = *(const int4*)(src + (size_t)nc * 16 + 12);
        float ks[8] = {0.f,0.f,0.f,0.f,0.f,0.f,0.f,0.f};
#define GAT(sn) {                                                             \
        u16x8 kv = *(const u16x8*)(kloc_a + (size_t)(sn) * 32 + g * 8);       \
        _Pragma("unroll")                                                     \
        for (int j = 0; j < 8; j++) ks[j] += b2f(kv[j]);                      \
    }
        GAT(si0.x) GAT(si0.y) GAT(si0.z) GAT(si0.w)
        GAT(si1.x) GAT(si1.y) GAT(si1.z) GAT(si1.w)
        GAT(si2.x) GAT(si2.y) GAT(si2.z) GAT(si2.w)
        GAT(si3.x) GAT(si3.y) GAT(si3.z) GAT(si3.w)
#undef GAT
        float se[8], sl[8], sg[8];
        float tt = 0.f;
#pragma unroll
        for (int j = 0; j < 8; j++) {
            float e = b2f(e8[j]) * inv;
            se[j] = e * e;
            sl[j] = b2f(q8[j]) * ks[j] * scl;
            sg[j] = b2f(g8[j]) * kg[j] * scg;
            tt += se[j] + sl[j] + sg[j];
        }
        tt += __shfl_xor(tt, 16);
        tt += __shfl_xor(tt, 32);
        float is = 1.f / (0.001f + tt);
#pragma unroll
        for (int j = 0; j < 8; j++) {
            p0[j] = (short)f2b(se[j] * is);
            p1[j] = (short)f2b(sl[j] * is);
            p2[j] = (short)f2b(sg[j] * is);
        }
    }

    // ---- 4 groups of 8 oc-tiles: MFMA -> 32KB LDS -> 4KB NT streaming stores
    const int srow = w * 16 + lr;
    const int sxor = (srow & 7) << 4;
#pragma unroll
    for (int gi = 0; gi < 4; gi++) {
        if (gi) __syncthreads();             // prev writeback reads done
#pragma unroll
        for (int m2 = 0; m2 < 8; m2++) {
            const int m = gi * 8 + m2;
            const ushort* vp = Vt + (size_t)(m * 16 + lr) * 96 + g * 8;
            s16x8 a0 = *(const s16x8*)(vp);
            s16x8 a1 = *(const s16x8*)(vp + 32);
            s16x8 a2 = *(const s16x8*)(vp + 64);
            f32x4 dA = (f32x4){0.f,0.f,0.f,0.f};
            dA = __builtin_amdgcn_mfma_f32_16x16x32_bf16(a0, p0, dA, 0, 0, 0);
            dA = __builtin_amdgcn_mfma_f32_16x16x32_bf16(a1, p1, dA, 0, 0, 0);
            dA = __builtin_amdgcn_mfma_f32_16x16x32_bf16(a2, p2, dA, 0, 0, 0);
            float4 bb = *(const float4*)(biasvec + m * 16 + g * 4);
            float4 o4 = {dA[0]+bb.x, dA[1]+bb.y, dA[2]+bb.z, dA[3]+bb.w};
            *(float4*)(stg + srow * 512 + ((m2 * 64 + g * 16) ^ sxor)) = o4;
        }
        __syncthreads();
        // writeback: 8 iters x 4KB contiguous (2 rows x 512B per wave-instr)
#pragma unroll
        for (int k = 0; k < 8; k++) {
            const int lin = k * 1024 + t * 4;    // float idx in 64x128 tile
            const int row = lin >> 7, inrow = lin & 127;
            f32x4 v = *(const f32x4*)(stg + row * 512 +
                                      ((inrow * 4) ^ ((row & 7) << 4)));
            const int gnode = blockIdx.x * 64 + row;
            if (gnode < NNODES)
                __builtin_nontemporal_store(
                    v, (f32x4*)(out + (size_t)gnode * 512 + gi * 128 + inrow));
        }
    }
}

extern "C" void kernel_launch(void* const* d_in, const int* in_sizes, int n_in,
                              void* d_out, int out_size, void* d_ws, size_t ws_size,
                              hipStream_t stream) {
    (void)in_sizes; (void)n_in; (void)out_size; (void)ws_size;
    const int*   adj    = (const int*)d_in[0];    // row0 = src
    const float* x      = (const float*)d_in[1];
    const float* qk_ego = (const float*)d_in[2];
    const float* v_ego  = (const float*)d_in[3];
    const float* qlw    = (const float*)d_in[4];
    const float* klw    = (const float*)d_in[5];
    const float* vl     = (const float*)d_in[6];
    const float* qgw    = (const float*)d_in[7];
    const float* kgw    = (const float*)d_in[8];
    const float* vg     = (const float*)d_in[9];
    const float* bias_b = (const float*)d_in[10];
    float* out = (float*)d_out;
    float* ws  = (float*)d_ws;

    // ws layout (float offsets)
    float*  kacc    = ws;                          // 32
    float*  sums    = ws + 32;                     // 2
    float*  biasvec = ws + 64;                     // 512
    ushort* B1t     = (ushort*)(ws + 1024);        // 128*512 bf16 -> 32768 fl
    ushort* Vt      = (ushort*)(ws + 33792);       // 512*96 bf16  -> 24576 fl
    ushort* ego_a   = (ushort*)(ws + 65536);                // N*32 bf16
    ushort* qloc_a  = (ushort*)(ws + 65536 + 1600000);      // N*32 bf16
    ushort* kloc_a  = (ushort*)(ws + 65536 + 3200000);      // N*32 bf16
    ushort* qglob_a = (ushort*)(ws + 65536 + 4800000);      // N*32 bf16
    float*  xcs     = ws + 6465536;                         // NBLK*512 fp32
    float*  csum2   = ws + 6465536 + 400384;                // KRA*512 fp32

    (void)hipMemsetAsync(sums, 0, 2 * sizeof(float), stream);
    k_sumsig<<<32, 256, 0, stream>>>(qlw, qgw, sums);
    {
        int total = 128 * 512 + 512 * 96 + 512;
        k_prep<<<(total + 255) / 256, 256, 0, stream>>>(qk_ego, qlw, klw, qgw,
                                                        v_ego, vl, vg, bias_b,
                                                        B1t, Vt, biasvec);
    }
    k_projx<<<NBLK, 512, 0, stream>>>(x, B1t, ego_a, qloc_a, kloc_a, qglob_a, xcs);
    k_kredA<<<KRA, 256, 0, stream>>>(xcs, csum2);
    k_kredB<<<1, 256, 0, stream>>>(csum2, kgw, kacc);
    k_fused<<<(NNODES + 63) / 64, 256, 0, stream>>>(ego_a, qloc_a, kloc_a, qglob_a,
                                                    adj, kacc, sums, Vt, biasvec, out);
}